// Round 18
// baseline (163.890 us; speedup 1.0000x reference)
//
#include <hip/hip_runtime.h>
#include <hip/hip_bf16.h>
#include <stdint.h>

#define D_MODEL 1024
#define NHEAD 16
#define SEQ 2048
#define BATCH 4
#define DK 64
#define QKVSTR 3072

typedef __attribute__((ext_vector_type(8))) short short8;
typedef __attribute__((ext_vector_type(4))) float f32x4;
typedef __attribute__((ext_vector_type(16))) float f32x16;

#if __has_builtin(__builtin_amdgcn_exp2f)
#define EXP2(x) __builtin_amdgcn_exp2f(x)
#else
#define EXP2(x) exp2f(x)
#endif

__device__ inline unsigned short f2bf(float f) {
  unsigned int u = __builtin_bit_cast(unsigned int, f);
  unsigned int r = (u + 0x7fffu + ((u >> 16) & 1u)) >> 16;
  return (unsigned short)r;
}

__device__ inline unsigned int cvt_pk_bf16(float lo, float hi) {
  unsigned int d;
  asm("v_cvt_pk_bf16_f32 %0, %1, %2" : "=v"(d) : "v"(lo), "v"(hi));
  return d;
}

#define GLOAD_LDS16(g, l) \
  __builtin_amdgcn_global_load_lds((const __attribute__((address_space(1))) unsigned int*)(g), \
      (__attribute__((address_space(3))) unsigned int*)(l), 16, 0, 0)

// ---------------- f32 -> bf16 convert ----------------
__global__ void cvt_kernel(const float* __restrict__ in, unsigned short* __restrict__ out, int n) {
  int i = (blockIdx.x * 256 + threadIdx.x) * 8;
  if (i >= n) return;
  const float4* p = (const float4*)(in + i);
  float4 a = p[0], b = p[1];
  union { unsigned short u[8]; uint4 v; } r;
  r.u[0] = f2bf(a.x); r.u[1] = f2bf(a.y); r.u[2] = f2bf(a.z); r.u[3] = f2bf(a.w);
  r.u[4] = f2bf(b.x); r.u[5] = f2bf(b.y); r.u[6] = f2bf(b.z); r.u[7] = f2bf(b.w);
  *(uint4*)(out + i) = r.v;
}

// 4 weight matrices in one dispatch; outputs contiguous at out + by*n
__global__ void cvt4_kernel(const float* __restrict__ i0, const float* __restrict__ i1,
                            const float* __restrict__ i2, const float* __restrict__ i3,
                            unsigned short* __restrict__ out, int n) {
  const int by = blockIdx.y;
  const float* in = (by == 0) ? i0 : (by == 1) ? i1 : (by == 2) ? i2 : i3;
  unsigned short* o = out + (size_t)by * n;
  int i = (blockIdx.x * 256 + threadIdx.x) * 8;
  if (i >= n) return;
  const float4* p = (const float4*)(in + i);
  float4 a = p[0], b = p[1];
  union { unsigned short u[8]; uint4 v; } r;
  r.u[0] = f2bf(a.x); r.u[1] = f2bf(a.y); r.u[2] = f2bf(a.z); r.u[3] = f2bf(a.w);
  r.u[4] = f2bf(b.x); r.u[5] = f2bf(b.y); r.u[6] = f2bf(b.z); r.u[7] = f2bf(b.w);
  *(uint4*)(o + i) = r.v;
}

// ---------------- GEMM: C[M,N] = f(A[M,K] * B[N,K]^T + bias) ----------------
// m97-style: single 32KB LDS buffer, stage -> vmcnt(0)+barrier -> 32 MFMA -> barrier.
// A/B staged with per-8-row XOR chunk swizzle -> conflict-free fragment reads.
template <typename CT>
__global__ __launch_bounds__(256)
void gemm_bt(const unsigned short* __restrict__ A, const unsigned short* __restrict__ B,
             const float* __restrict__ b0, const float* __restrict__ b1,
             const float* __restrict__ b2, CT* __restrict__ C, int M, int N, int K,
             int qcols, float alphaQ) {
  __shared__ unsigned short As[128 * 64];
  __shared__ unsigned short Bs[128 * 64];
  const int t = threadIdx.x;
  const int l = t & 63;
  const int w = t >> 6;
  const int wr = w >> 1, wc = w & 1;
  const int l15 = l & 15, lg = l >> 4;
  const int m0 = blockIdx.y * 128, n0 = blockIdx.x * 128;

  f32x4 acc[4][4] = {};

  const int srow = t >> 3;           // 0..31
  const int sc8 = t & 7;             // dest 16B chunk
  const int kssw = sc8 ^ (srow & 7); // XOR-swizzled source chunk

  const unsigned short* ap = A + (size_t)(m0 + srow) * K + kssw * 8;
  const unsigned short* bp = B + (size_t)(n0 + srow) * K + kssw * 8;

  const int nt = K >> 6;
  for (int kt = 0; kt < nt; ++kt) {
    const int k0 = kt * 64;
    #pragma unroll
    for (int j = 0; j < 4; ++j) {
      GLOAD_LDS16(ap + (size_t)(j * 32) * K + k0, &As[(j * 32 + srow) * 64 + sc8 * 8]);
      GLOAD_LDS16(bp + (size_t)(j * 32) * K + k0, &Bs[(j * 32 + srow) * 64 + sc8 * 8]);
    }
    asm volatile("s_waitcnt vmcnt(0)" ::: "memory");
    __builtin_amdgcn_s_barrier();
    __builtin_amdgcn_sched_barrier(0);

    __builtin_amdgcn_s_setprio(1);
    #pragma unroll
    for (int kk = 0; kk < 2; ++kk) {
      short8 af[4], bfr[4];
      #pragma unroll
      for (int m = 0; m < 4; ++m) {
        int row = wr * 64 + m * 16 + l15;
        af[m] = *(const short8*)&As[row * 64 + (((kk * 4 + lg) ^ (row & 7)) * 8)];
      }
      #pragma unroll
      for (int n = 0; n < 4; ++n) {
        int row = wc * 64 + n * 16 + l15;
        bfr[n] = *(const short8*)&Bs[row * 64 + (((kk * 4 + lg) ^ (row & 7)) * 8)];
      }
      #pragma unroll
      for (int m = 0; m < 4; ++m)
        #pragma unroll
        for (int n = 0; n < 4; ++n)
          acc[m][n] = __builtin_amdgcn_mfma_f32_16x16x32_bf16(af[m], bfr[n], acc[m][n], 0, 0, 0);
    }
    __builtin_amdgcn_s_setprio(0);

    __builtin_amdgcn_s_barrier();
    __builtin_amdgcn_sched_barrier(0);
  }

  #pragma unroll
  for (int m = 0; m < 4; ++m) {
    #pragma unroll
    for (int n = 0; n < 4; ++n) {
      int col = n0 + wc * 64 + n * 16 + l15;
      const float* bp2 = (col < 1024) ? b0 : (col < 2048) ? b1 : b2;
      float bz = bp2[col & 1023];
      #pragma unroll
      for (int r = 0; r < 4; ++r) {
        int row = m0 + wr * 64 + m * 16 + lg * 4 + r;
        float v = acc[m][n][r] + bz;
        if (col < qcols) v *= alphaQ;
        if constexpr (sizeof(CT) == 2) {
          C[(size_t)row * N + col] = (CT)f2bf(v);
        } else {
          C[(size_t)row * N + col] = v;
        }
      }
    }
  }
}

// ---------------- causal flash attention: 32x32 MFMA, 64 q-rows/wave, register-P ----------------
// QKV: [B*S, 3072] bf16 rows = [Q | K | V], head h at col h*64 within each section.
// Q pre-scaled by 0.125*log2(e); fixed-shift exp2 softmax (scores are O(1), no overflow).
// Block covers 256 q-rows; wave w owns lo-tile (base + w*32) AND hi-tile (base + 128 + w*32).
// Each K/V LDS fragment is read ONCE and feeds BOTH q-tiles (4 MFMAs per fragment pair)
// -> per-q LDS traffic halves vs one-tile/wave. Lo-tile skips its trailing kv-tiles.
// PV as O^T = V^T * P^T with in-register P (cvt_pk); kv bit2<->bit3 permutation absorbed
// into V staging slot. Pipeline: K(t+1) DMA (dbuf) + V(t+1) reg loads across barrier2.
__global__ __launch_bounds__(256, 2)
void attn_kernel(const unsigned short* __restrict__ QKV, unsigned short* __restrict__ AO) {
  __shared__ unsigned short Ks[2][64 * 64];
  __shared__ unsigned int Vt32[64 * 33];       // [d][pair-slot] packed 2xbf16; stride 33 dwords

  const int t = threadIdx.x;
  const int l = t & 63;
  const int wave = t >> 6;
  const int l31 = l & 31, lh = l >> 5;
  const int id = blockIdx.x;
  const int qs = 7 - (id >> 6);   // heaviest q-super-tiles dispatched first
  const int bh = id & 63;         // same-head blocks differ by 64 -> same XCD
  const int b = bh >> 4, h = bh & 15;
  const size_t hbase = (size_t)b * SEQ * QKVSTR + h * DK;
  const size_t hbaseO = (size_t)b * SEQ * D_MODEL + h * DK;

  const int qL = qs * 256 + wave * 32 + l31;   // lo-tile q row (this lane)
  const int qH = qL + 128;                     // hi-tile q row

  // hoisted Q fragments for both q-tiles (B-operand)
  short8 qfL[4], qfH[4];
  {
    const unsigned short* qp = QKV + hbase + (size_t)qL * QKVSTR + lh * 8;
    qfL[0] = *(const short8*)(qp);
    qfL[1] = *(const short8*)(qp + 16);
    qfL[2] = *(const short8*)(qp + 32);
    qfL[3] = *(const short8*)(qp + 48);
    qp = QKV + hbase + (size_t)qH * QKVSTR + lh * 8;
    qfH[0] = *(const short8*)(qp);
    qfH[1] = *(const short8*)(qp + 16);
    qfH[2] = *(const short8*)(qp + 32);
    qfH[3] = *(const short8*)(qp + 48);
  }

  f32x16 oL0 = {}, oL1 = {}, oH0 = {}, oH1 = {};
  float laccL = 0.f, laccH = 0.f;

  // K staging map: thread t covers row srow(+32), 16B chunk sc8; source chunk XOR-swizzled
  const int srow = t >> 3, sc8 = t & 7;
  const int kssw = sc8 ^ (srow & 7);
  // V staging: thread covers kv-pair vp_, 8 d values; slot = swap bits 1,2 of vp_
  const int vp_ = t & 31;
  const int vdh = (t >> 5) * 8;
  const int vpos = (vp_ & 0x19) | ((vp_ & 2) << 1) | ((vp_ & 4) >> 1);

  auto issueK = [&](int kvt, int buf) {
    const unsigned short* kp = QKV + hbase + 1024 + (size_t)(kvt * 64 + srow) * QKVSTR + kssw * 8;
    GLOAD_LDS16(kp, &Ks[buf][srow * 64 + sc8 * 8]);
    GLOAD_LDS16(kp + (size_t)32 * QKVSTR, &Ks[buf][(32 + srow) * 64 + sc8 * 8]);
  };

  const int ntiles = 4 * qs + 4;   // hi-tile kv-tiles
  const int nA = 4 * qs + 2;       // lo-tile kv-tiles

  // prologue: tile 0 staged
  short8 cv0, cv1;
  issueK(0, 0);
  {
    const unsigned short* vp = QKV + hbase + 2048 + (size_t)(2 * vp_) * QKVSTR + vdh;
    cv0 = *(const short8*)vp;
    cv1 = *(const short8*)(vp + QKVSTR);
  }

  int p = 0;
  for (int kvt = 0; kvt < ntiles; ++kvt) {
    const int kv0 = kvt * 64;
    // barrier1: my K(t) DMA + V(t) regs arrived; all waves done with Vt(t-1) reads
    asm volatile("s_waitcnt vmcnt(0)" ::: "memory");
    __builtin_amdgcn_s_barrier();
    __builtin_amdgcn_sched_barrier(0);

    // stage V(t) to LDS (packed transpose, permuted slot), then prefetch tile t+1
    #pragma unroll
    for (int j = 0; j < 8; ++j) {
      unsigned int dw = (unsigned int)(unsigned short)cv0[j] |
                        ((unsigned int)(unsigned short)cv1[j] << 16);
      Vt32[(vdh + j) * 33 + vpos] = dw;
    }
    short8 nv0 = cv0, nv1 = cv1;
    if (kvt + 1 < ntiles) {
      issueK(kvt + 1, p ^ 1);
      const unsigned short* vp = QKV + hbase + 2048 + (size_t)(kv0 + 64 + 2 * vp_) * QKVSTR + vdh;
      nv0 = *(const short8*)vp;
      nv1 = *(const short8*)(vp + QKVSTR);
    }
    // barrier2: V writes visible; prefetch loads stay in flight (no vmcnt drain)
    asm volatile("s_waitcnt lgkmcnt(0)" ::: "memory");
    __builtin_amdgcn_s_barrier();
    __builtin_amdgcn_sched_barrier(0);

    const bool loAct = (kvt < nA);

    // ---- merged swapped QK^T (32x32x16): each kf pair feeds both q-tiles ----
    f32x16 sL0 = {}, sL1 = {}, sH0 = {}, sH1 = {};
    __builtin_amdgcn_s_setprio(1);
    #pragma unroll
    for (int kg = 0; kg < 4; ++kg) {
      int row0 = l31;
      int row1 = 32 + l31;
      int c = 2 * kg + lh;
      short8 kf0 = *(const short8*)&Ks[p][row0 * 64 + ((c ^ (row0 & 7)) * 8)];
      short8 kf1 = *(const short8*)&Ks[p][row1 * 64 + ((c ^ (row1 & 7)) * 8)];
      if (loAct) {
        sL0 = __builtin_amdgcn_mfma_f32_32x32x16_bf16(kf0, qfL[kg], sL0, 0, 0, 0);
        sL1 = __builtin_amdgcn_mfma_f32_32x32x16_bf16(kf1, qfL[kg], sL1, 0, 0, 0);
      }
      sH0 = __builtin_amdgcn_mfma_f32_32x32x16_bf16(kf0, qfH[kg], sH0, 0, 0, 0);
      sH1 = __builtin_amdgcn_mfma_f32_32x32x16_bf16(kf1, qfH[kg], sH1, 0, 0, 0);
    }
    __builtin_amdgcn_s_setprio(0);

    // ---- causal masks ----
    if (loAct && kvt >= nA - 2) {
      #pragma unroll
      for (int g = 0; g < 4; ++g)
        #pragma unroll
        for (int e = 0; e < 4; ++e) {
          int kvl = 8 * g + e + 4 * lh;
          if (kv0 + kvl > qL)      sL0[4 * g + e] = -INFINITY;
          if (kv0 + 32 + kvl > qL) sL1[4 * g + e] = -INFINITY;
        }
    }
    if (kvt >= ntiles - 2) {
      #pragma unroll
      for (int g = 0; g < 4; ++g)
        #pragma unroll
        for (int e = 0; e < 4; ++e) {
          int kvl = 8 * g + e + 4 * lh;
          if (kv0 + kvl > qH)      sH0[4 * g + e] = -INFINITY;
          if (kv0 + 32 + kvl > qH) sH1[4 * g + e] = -INFINITY;
        }
    }

    // ---- softmax, fixed shift: P = exp2(s); lane-local sums ----
    if (loAct) {
      float ps0 = 0.f, ps1 = 0.f;
      #pragma unroll
      for (int i = 0; i < 16; ++i) {
        sL0[i] = EXP2(sL0[i]); ps0 += sL0[i];
        sL1[i] = EXP2(sL1[i]); ps1 += sL1[i];
      }
      float ps = ps0 + ps1;
      ps += __shfl_xor(ps, 32, 64);
      laccL += ps;
    }
    {
      float ps0 = 0.f, ps1 = 0.f;
      #pragma unroll
      for (int i = 0; i < 16; ++i) {
        sH0[i] = EXP2(sH0[i]); ps0 += sH0[i];
        sH1[i] = EXP2(sH1[i]); ps1 += sH1[i];
      }
      float ps = ps0 + ps1;
      ps += __shfl_xor(ps, 32, 64);
      laccH += ps;
    }

    // ---- PV: each V fragment pair feeds both q-tiles ----
    __builtin_amdgcn_s_setprio(1);
    #pragma unroll
    for (int win = 0; win < 4; ++win) {
      const int base = 8 * (win & 1);
      uint4 u0 = *(const uint4*)&Vt32[(l31) * 33 + win * 8 + lh * 4];
      uint4 u1 = *(const uint4*)&Vt32[(32 + l31) * 33 + win * 8 + lh * 4];
      short8 vf0 = __builtin_bit_cast(short8, u0);
      short8 vf1 = __builtin_bit_cast(short8, u1);
      uint4 pu;
      if (loAct) {
        if (win < 2) {
          pu.x = cvt_pk_bf16(sL0[base + 0], sL0[base + 1]);
          pu.y = cvt_pk_bf16(sL0[base + 2], sL0[base + 3]);
          pu.z = cvt_pk_bf16(sL0[base + 4], sL0[base + 5]);
          pu.w = cvt_pk_bf16(sL0[base + 6], sL0[base + 7]);
        } else {
          pu.x = cvt_pk_bf16(sL1[base + 0], sL1[base + 1]);
          pu.y = cvt_pk_bf16(sL1[base + 2], sL1[base + 3]);
          pu.z = cvt_pk_bf16(sL1[base + 4], sL1[base + 5]);
          pu.w = cvt_pk_bf16(sL1[base + 6], sL1[base + 7]);
        }
        short8 pb = __builtin_bit_cast(short8, pu);
        oL0 = __builtin_amdgcn_mfma_f32_32x32x16_bf16(vf0, pb, oL0, 0, 0, 0);
        oL1 = __builtin_amdgcn_mfma_f32_32x32x16_bf16(vf1, pb, oL1, 0, 0, 0);
      }
      if (win < 2) {
        pu.x = cvt_pk_bf16(sH0[base + 0], sH0[base + 1]);
        pu.y = cvt_pk_bf16(sH0[base + 2], sH0[base + 3]);
        pu.z = cvt_pk_bf16(sH0[base + 4], sH0[base + 5]);
        pu.w = cvt_pk_bf16(sH0[base + 6], sH0[base + 7]);
      } else {
        pu.x = cvt_pk_bf16(sH1[base + 0], sH1[base + 1]);
        pu.y = cvt_pk_bf16(sH1[base + 2], sH1[base + 3]);
        pu.z = cvt_pk_bf16(sH1[base + 4], sH1[base + 5]);
        pu.w = cvt_pk_bf16(sH1[base + 6], sH1[base + 7]);
      }
      short8 pb = __builtin_bit_cast(short8, pu);
      oH0 = __builtin_amdgcn_mfma_f32_32x32x16_bf16(vf0, pb, oH0, 0, 0, 0);
      oH1 = __builtin_amdgcn_mfma_f32_32x32x16_bf16(vf1, pb, oH1, 0, 0, 0);
    }
    __builtin_amdgcn_s_setprio(0);

    cv0 = nv0; cv1 = nv1;
    p ^= 1;
  }

  // ---- write normalized outputs: lane-local inv, O^T rows are d, col is q ----
  float invL = 1.f / laccL;
  float invH = 1.f / laccH;
  unsigned short* opL = AO + hbaseO + (size_t)qL * D_MODEL;
  unsigned short* opH = AO + hbaseO + (size_t)qH * D_MODEL;
  #pragma unroll
  for (int g = 0; g < 4; ++g) {
    int d0 = 8 * g + 4 * lh;
    ushort4 v0, v1;
    v0.x = f2bf(oL0[4 * g + 0] * invL); v0.y = f2bf(oL0[4 * g + 1] * invL);
    v0.z = f2bf(oL0[4 * g + 2] * invL); v0.w = f2bf(oL0[4 * g + 3] * invL);
    v1.x = f2bf(oL1[4 * g + 0] * invL); v1.y = f2bf(oL1[4 * g + 1] * invL);
    v1.z = f2bf(oL1[4 * g + 2] * invL); v1.w = f2bf(oL1[4 * g + 3] * invL);
    *(ushort4*)(opL + d0) = v0;
    *(ushort4*)(opL + 32 + d0) = v1;
    v0.x = f2bf(oH0[4 * g + 0] * invH); v0.y = f2bf(oH0[4 * g + 1] * invH);
    v0.z = f2bf(oH0[4 * g + 2] * invH); v0.w = f2bf(oH0[4 * g + 3] * invH);
    v1.x = f2bf(oH1[4 * g + 0] * invH); v1.y = f2bf(oH1[4 * g + 1] * invH);
    v1.z = f2bf(oH1[4 * g + 2] * invH); v1.w = f2bf(oH1[4 * g + 3] * invH);
    *(ushort4*)(opH + d0) = v0;
    *(ushort4*)(opH + 32 + d0) = v1;
  }
}

extern "C" void kernel_launch(void* const* d_in, const int* in_sizes, int n_in,
                              void* d_out, int out_size, void* d_ws, size_t ws_size,
                              hipStream_t stream) {
  const float* x   = (const float*)d_in[0];
  const float* WQw = (const float*)d_in[1];
  const float* WQb = (const float*)d_in[2];
  const float* WKw = (const float*)d_in[3];
  const float* WKb = (const float*)d_in[4];
  const float* WVw = (const float*)d_in[5];
  const float* WVb = (const float*)d_in[6];
  const float* WOw = (const float*)d_in[7];
  const float* WOb = (const float*)d_in[8];
  float* out = (float*)d_out;

  const int M = BATCH * SEQ;       // 8192
  const int D = D_MODEL;           // 1024
  const int NX = M * D;            // 8388608
  const int NW = D * D;            // 1048576

  unsigned short* xb = (unsigned short*)d_ws;
  unsigned short* wq = xb + NX;        // wq|wk|wv|wo contiguous (cvt4)
  unsigned short* wo = wq + 3 * NW;
  unsigned short* QKVb = wq + 4 * NW;  // [8192][3072]
  unsigned short* AOb = xb;            // reuse x-bf16 region after QKV projection

  cvt_kernel<<<NX / 8 / 256, 256, 0, stream>>>(x, xb, NX);
  cvt4_kernel<<<dim3(NW / 8 / 256, 4), 256, 0, stream>>>(WQw, WKw, WVw, WOw, wq, NW);

  const float qscale = 0.125f * 1.4426950408889634f;  // softmax scale + log2(e) folded into Q
  // fused QKV projection: [8192,1024] x [3072,1024]^T -> [8192,3072]
  gemm_bt<unsigned short><<<dim3(3 * D / 128, M / 128), 256, 0, stream>>>(
      xb, wq, WQb, WKb, WVb, QKVb, M, 3 * D, D, 1024, qscale);

  attn_kernel<<<512, 256, 0, stream>>>(QKVb, AOb);

  gemm_bt<float><<<dim3(D / 128, M / 128), 256, 0, stream>>>(
      AOb, wo, WOb, WOb, WOb, out, M, D, D, 0, 1.0f);
}

// Round 19
// 150.749 us; speedup vs baseline: 1.0872x; 1.0872x over previous
//
#include <hip/hip_runtime.h>
#include <hip/hip_bf16.h>
#include <stdint.h>

#define D_MODEL 1024
#define NHEAD 16
#define SEQ 2048
#define BATCH 4
#define DK 64
#define QKVSTR 3072

typedef __attribute__((ext_vector_type(8))) short short8;
typedef __attribute__((ext_vector_type(4))) float f32x4;
typedef __attribute__((ext_vector_type(16))) float f32x16;

#if __has_builtin(__builtin_amdgcn_exp2f)
#define EXP2(x) __builtin_amdgcn_exp2f(x)
#else
#define EXP2(x) exp2f(x)
#endif

__device__ inline unsigned short f2bf(float f) {
  unsigned int u = __builtin_bit_cast(unsigned int, f);
  unsigned int r = (u + 0x7fffu + ((u >> 16) & 1u)) >> 16;
  return (unsigned short)r;
}

__device__ inline unsigned int cvt_pk_bf16(float lo, float hi) {
  unsigned int d;
  asm("v_cvt_pk_bf16_f32 %0, %1, %2" : "=v"(d) : "v"(lo), "v"(hi));
  return d;
}

#define GLOAD_LDS16(g, l) \
  __builtin_amdgcn_global_load_lds((const __attribute__((address_space(1))) unsigned int*)(g), \
      (__attribute__((address_space(3))) unsigned int*)(l), 16, 0, 0)

// ---------------- f32 -> bf16 convert ----------------
__global__ void cvt_kernel(const float* __restrict__ in, unsigned short* __restrict__ out, int n) {
  int i = (blockIdx.x * 256 + threadIdx.x) * 8;
  if (i >= n) return;
  const float4* p = (const float4*)(in + i);
  float4 a = p[0], b = p[1];
  union { unsigned short u[8]; uint4 v; } r;
  r.u[0] = f2bf(a.x); r.u[1] = f2bf(a.y); r.u[2] = f2bf(a.z); r.u[3] = f2bf(a.w);
  r.u[4] = f2bf(b.x); r.u[5] = f2bf(b.y); r.u[6] = f2bf(b.z); r.u[7] = f2bf(b.w);
  *(uint4*)(out + i) = r.v;
}

// 4 weight matrices in one dispatch; outputs contiguous at out + by*n
__global__ void cvt4_kernel(const float* __restrict__ i0, const float* __restrict__ i1,
                            const float* __restrict__ i2, const float* __restrict__ i3,
                            unsigned short* __restrict__ out, int n) {
  const int by = blockIdx.y;
  const float* in = (by == 0) ? i0 : (by == 1) ? i1 : (by == 2) ? i2 : i3;
  unsigned short* o = out + (size_t)by * n;
  int i = (blockIdx.x * 256 + threadIdx.x) * 8;
  if (i >= n) return;
  const float4* p = (const float4*)(in + i);
  float4 a = p[0], b = p[1];
  union { unsigned short u[8]; uint4 v; } r;
  r.u[0] = f2bf(a.x); r.u[1] = f2bf(a.y); r.u[2] = f2bf(a.z); r.u[3] = f2bf(a.w);
  r.u[4] = f2bf(b.x); r.u[5] = f2bf(b.y); r.u[6] = f2bf(b.z); r.u[7] = f2bf(b.w);
  *(uint4*)(o + i) = r.v;
}

// ---------------- GEMM: C[M,N] = f(A[M,K] * B[N,K]^T + bias) ----------------
// m97-style: single 32KB LDS buffer, stage -> vmcnt(0)+barrier -> 32 MFMA -> barrier.
// A/B staged with per-8-row XOR chunk swizzle -> conflict-free fragment reads.
template <typename CT>
__global__ __launch_bounds__(256)
void gemm_bt(const unsigned short* __restrict__ A, const unsigned short* __restrict__ B,
             const float* __restrict__ b0, const float* __restrict__ b1,
             const float* __restrict__ b2, CT* __restrict__ C, int M, int N, int K,
             int qcols, float alphaQ) {
  __shared__ unsigned short As[128 * 64];
  __shared__ unsigned short Bs[128 * 64];
  const int t = threadIdx.x;
  const int l = t & 63;
  const int w = t >> 6;
  const int wr = w >> 1, wc = w & 1;
  const int l15 = l & 15, lg = l >> 4;
  const int m0 = blockIdx.y * 128, n0 = blockIdx.x * 128;

  f32x4 acc[4][4] = {};

  const int srow = t >> 3;           // 0..31
  const int sc8 = t & 7;             // dest 16B chunk
  const int kssw = sc8 ^ (srow & 7); // XOR-swizzled source chunk

  const unsigned short* ap = A + (size_t)(m0 + srow) * K + kssw * 8;
  const unsigned short* bp = B + (size_t)(n0 + srow) * K + kssw * 8;

  const int nt = K >> 6;
  for (int kt = 0; kt < nt; ++kt) {
    const int k0 = kt * 64;
    #pragma unroll
    for (int j = 0; j < 4; ++j) {
      GLOAD_LDS16(ap + (size_t)(j * 32) * K + k0, &As[(j * 32 + srow) * 64 + sc8 * 8]);
      GLOAD_LDS16(bp + (size_t)(j * 32) * K + k0, &Bs[(j * 32 + srow) * 64 + sc8 * 8]);
    }
    asm volatile("s_waitcnt vmcnt(0)" ::: "memory");
    __builtin_amdgcn_s_barrier();
    __builtin_amdgcn_sched_barrier(0);

    __builtin_amdgcn_s_setprio(1);
    #pragma unroll
    for (int kk = 0; kk < 2; ++kk) {
      short8 af[4], bfr[4];
      #pragma unroll
      for (int m = 0; m < 4; ++m) {
        int row = wr * 64 + m * 16 + l15;
        af[m] = *(const short8*)&As[row * 64 + (((kk * 4 + lg) ^ (row & 7)) * 8)];
      }
      #pragma unroll
      for (int n = 0; n < 4; ++n) {
        int row = wc * 64 + n * 16 + l15;
        bfr[n] = *(const short8*)&Bs[row * 64 + (((kk * 4 + lg) ^ (row & 7)) * 8)];
      }
      #pragma unroll
      for (int m = 0; m < 4; ++m)
        #pragma unroll
        for (int n = 0; n < 4; ++n)
          acc[m][n] = __builtin_amdgcn_mfma_f32_16x16x32_bf16(af[m], bfr[n], acc[m][n], 0, 0, 0);
    }
    __builtin_amdgcn_s_setprio(0);

    __builtin_amdgcn_s_barrier();
    __builtin_amdgcn_sched_barrier(0);
  }

  #pragma unroll
  for (int m = 0; m < 4; ++m) {
    #pragma unroll
    for (int n = 0; n < 4; ++n) {
      int col = n0 + wc * 64 + n * 16 + l15;
      const float* bp2 = (col < 1024) ? b0 : (col < 2048) ? b1 : b2;
      float bz = bp2[col & 1023];
      #pragma unroll
      for (int r = 0; r < 4; ++r) {
        int row = m0 + wr * 64 + m * 16 + lg * 4 + r;
        float v = acc[m][n][r] + bz;
        if (col < qcols) v *= alphaQ;
        if constexpr (sizeof(CT) == 2) {
          C[(size_t)row * N + col] = (CT)f2bf(v);
        } else {
          C[(size_t)row * N + col] = v;
        }
      }
    }
  }
}

// ---------------- causal flash attention: 32x32 MFMA, swapped QK^T, register-P ----------------
// QKV: [B*S, 3072] bf16 rows = [Q | K | V], head h at col h*64 within each section.
// Q pre-scaled by 0.125*log2(e); fixed-shift exp2 softmax (scores are O(1) -> no overflow;
// normalization o/lacc makes the missing per-row shift exact).
// Wave covers 32 q-rows; lane owns ONE q = q0 + (lane&31) (lane-local stats).
// lacc is accumulated as lane-local PARTIAL sums (each lane covers its kv-subset);
// the single cross-lane combine (shfl_xor 32) happens once at the end, not per tile.
// PV as O^T = V^T * P^T: P packed in-register (cvt_pk); kv permutation (swap bits 2,3
// of kv mod 16) applied to BOTH P slot-order (implicit) and V staging slot (vpos).
// Pipeline: K(t+1) DMA (dbuf Ks) + V(t+1) reg loads in flight across barrier2 (lgkm-only).
__global__ __launch_bounds__(256, 2)
void attn_kernel(const unsigned short* __restrict__ QKV, unsigned short* __restrict__ AO) {
  __shared__ unsigned short Ks[2][64 * 64];
  __shared__ unsigned int Vt32[64 * 33];       // [d][pair-slot] packed 2xbf16; stride 33 dwords

  const int t = threadIdx.x;
  const int l = t & 63;
  const int wave = t >> 6;
  const int l31 = l & 31, lh = l >> 5;
  const int id = blockIdx.x;
  const int qb = 15 - (id >> 6);  // heaviest q-blocks dispatched first
  const int bh = id & 63;         // same-head blocks differ by 64 -> same XCD
  const int b = bh >> 4, h = bh & 15;
  const size_t hbase = (size_t)b * SEQ * QKVSTR + h * DK;
  const size_t hbaseO = (size_t)b * SEQ * D_MODEL + h * DK;

  const int q = qb * 128 + wave * 32 + l31;    // this lane's q row

  // hoisted Q fragments (B-operand): qf[kg][j] = Q[q][kg*16 + lh*8 + j]
  short8 qf[4];
  {
    const unsigned short* qp = QKV + hbase + (size_t)q * QKVSTR + lh * 8;
    qf[0] = *(const short8*)(qp);
    qf[1] = *(const short8*)(qp + 16);
    qf[2] = *(const short8*)(qp + 32);
    qf[3] = *(const short8*)(qp + 48);
  }

  f32x16 o0 = {}, o1 = {};        // O^T accumulators: d-tiles 0 (d 0..31), 1 (d 32..63)
  float lacc = 0.f;               // lane-local partial row-sum (combined once at end)

  // K staging map: thread t covers row srow(+32), 16B chunk sc8; source chunk XOR-swizzled
  const int srow = t >> 3, sc8 = t & 7;
  const int kssw = sc8 ^ (srow & 7);
  // V staging: thread covers kv-pair vp_, 8 d values; slot = swap bits 1,2 of vp_ (pi on kv bits 2,3)
  const int vp_ = t & 31;
  const int vdh = (t >> 5) * 8;
  const int vpos = (vp_ & 0x19) | ((vp_ & 2) << 1) | ((vp_ & 4) >> 1);

  auto issueK = [&](int kvt, int buf) {
    const unsigned short* kp = QKV + hbase + 1024 + (size_t)(kvt * 64 + srow) * QKVSTR + kssw * 8;
    GLOAD_LDS16(kp, &Ks[buf][srow * 64 + sc8 * 8]);
    GLOAD_LDS16(kp + (size_t)32 * QKVSTR, &Ks[buf][(32 + srow) * 64 + sc8 * 8]);
  };

  const int ntiles = 2 * qb + 2;

  // prologue: tile 0 staged
  short8 cv0, cv1;
  issueK(0, 0);
  {
    const unsigned short* vp = QKV + hbase + 2048 + (size_t)(2 * vp_) * QKVSTR + vdh;
    cv0 = *(const short8*)vp;
    cv1 = *(const short8*)(vp + QKVSTR);
  }

  int p = 0;
  for (int kvt = 0; kvt < ntiles; ++kvt) {
    const int kv0 = kvt * 64;
    // barrier1: my K(t) DMA + V(t) regs arrived; all waves done with Vt(t-1) reads
    asm volatile("s_waitcnt vmcnt(0)" ::: "memory");
    __builtin_amdgcn_s_barrier();
    __builtin_amdgcn_sched_barrier(0);

    // stage V(t) to LDS (packed transpose, permuted slot), then prefetch tile t+1
    #pragma unroll
    for (int j = 0; j < 8; ++j) {
      unsigned int dw = (unsigned int)(unsigned short)cv0[j] |
                        ((unsigned int)(unsigned short)cv1[j] << 16);
      Vt32[(vdh + j) * 33 + vpos] = dw;
    }
    short8 nv0 = cv0, nv1 = cv1;
    if (kvt + 1 < ntiles) {
      issueK(kvt + 1, p ^ 1);
      const unsigned short* vp = QKV + hbase + 2048 + (size_t)(kv0 + 64 + 2 * vp_) * QKVSTR + vdh;
      nv0 = *(const short8*)vp;
      nv1 = *(const short8*)(vp + QKVSTR);
    }
    // barrier2: V writes visible; prefetch loads stay in flight (no vmcnt drain)
    asm volatile("s_waitcnt lgkmcnt(0)" ::: "memory");
    __builtin_amdgcn_s_barrier();
    __builtin_amdgcn_sched_barrier(0);

    // ---- swapped QK^T (32x32x16): s0 = S^T[kv 0..31][q], s1 = S^T[kv 32..63][q] ----
    f32x16 s0 = {}, s1 = {};
    __builtin_amdgcn_s_setprio(1);
    #pragma unroll
    for (int kg = 0; kg < 4; ++kg) {
      int row0 = l31;            // kv-local, half 0
      int row1 = 32 + l31;       // kv-local, half 1
      int c = 2 * kg + lh;
      short8 kf0 = *(const short8*)&Ks[p][row0 * 64 + ((c ^ (row0 & 7)) * 8)];
      short8 kf1 = *(const short8*)&Ks[p][row1 * 64 + ((c ^ (row1 & 7)) * 8)];
      s0 = __builtin_amdgcn_mfma_f32_32x32x16_bf16(kf0, qf[kg], s0, 0, 0, 0);
      s1 = __builtin_amdgcn_mfma_f32_32x32x16_bf16(kf1, qf[kg], s1, 0, 0, 0);
    }
    __builtin_amdgcn_s_setprio(0);

    // ---- causal mask (last two kv-tiles only) ----
    if (kvt >= ntiles - 2) {
      #pragma unroll
      for (int g = 0; g < 4; ++g)
        #pragma unroll
        for (int e = 0; e < 4; ++e) {
          int kvl = 8 * g + e + 4 * lh;
          if (kv0 + kvl > q)      s0[4 * g + e] = -INFINITY;
          if (kv0 + 32 + kvl > q) s1[4 * g + e] = -INFINITY;
        }
    }

    // ---- softmax, fixed shift: P = exp2(s); lane-local partial sums only ----
    {
      float ps0 = 0.f, ps1 = 0.f, ps2 = 0.f, ps3 = 0.f;
      #pragma unroll
      for (int i = 0; i < 4; ++i) {
        s0[i]      = EXP2(s0[i]);      ps0 += s0[i];
        s0[i + 4]  = EXP2(s0[i + 4]);  ps1 += s0[i + 4];
        s0[i + 8]  = EXP2(s0[i + 8]);  ps2 += s0[i + 8];
        s0[i + 12] = EXP2(s0[i + 12]); ps3 += s0[i + 12];
      }
      #pragma unroll
      for (int i = 0; i < 4; ++i) {
        s1[i]      = EXP2(s1[i]);      ps0 += s1[i];
        s1[i + 4]  = EXP2(s1[i + 4]);  ps1 += s1[i + 4];
        s1[i + 8]  = EXP2(s1[i + 8]);  ps2 += s1[i + 8];
        s1[i + 12] = EXP2(s1[i + 12]); ps3 += s1[i + 12];
      }
      lacc += (ps0 + ps1) + (ps2 + ps3);
    }

    // ---- PV: O^T += V^T * P^T, P packed in-register per 16-kv window ----
    __builtin_amdgcn_s_setprio(1);
    #pragma unroll
    for (int win = 0; win < 4; ++win) {
      const int base = 8 * (win & 1);
      uint4 pu;
      if (win < 2) {
        pu.x = cvt_pk_bf16(s0[base + 0], s0[base + 1]);
        pu.y = cvt_pk_bf16(s0[base + 2], s0[base + 3]);
        pu.z = cvt_pk_bf16(s0[base + 4], s0[base + 5]);
        pu.w = cvt_pk_bf16(s0[base + 6], s0[base + 7]);
      } else {
        pu.x = cvt_pk_bf16(s1[base + 0], s1[base + 1]);
        pu.y = cvt_pk_bf16(s1[base + 2], s1[base + 3]);
        pu.z = cvt_pk_bf16(s1[base + 4], s1[base + 5]);
        pu.w = cvt_pk_bf16(s1[base + 6], s1[base + 7]);
      }
      short8 pb = __builtin_bit_cast(short8, pu);
      uint4 u0 = *(const uint4*)&Vt32[(l31) * 33 + win * 8 + lh * 4];
      uint4 u1 = *(const uint4*)&Vt32[(32 + l31) * 33 + win * 8 + lh * 4];
      o0 = __builtin_amdgcn_mfma_f32_32x32x16_bf16(__builtin_bit_cast(short8, u0), pb, o0, 0, 0, 0);
      o1 = __builtin_amdgcn_mfma_f32_32x32x16_bf16(__builtin_bit_cast(short8, u1), pb, o1, 0, 0, 0);
    }
    __builtin_amdgcn_s_setprio(0);

    cv0 = nv0; cv1 = nv1;
    p ^= 1;
  }

  // ---- combine lane-half partial sums once; write normalized output ----
  lacc += __shfl_xor(lacc, 32, 64);
  float inv = 1.f / lacc;
  unsigned short* op = AO + hbaseO + (size_t)q * D_MODEL;
  #pragma unroll
  for (int g = 0; g < 4; ++g) {
    int d0 = 8 * g + 4 * lh;
    ushort4 v0, v1;
    v0.x = f2bf(o0[4 * g + 0] * inv); v0.y = f2bf(o0[4 * g + 1] * inv);
    v0.z = f2bf(o0[4 * g + 2] * inv); v0.w = f2bf(o0[4 * g + 3] * inv);
    v1.x = f2bf(o1[4 * g + 0] * inv); v1.y = f2bf(o1[4 * g + 1] * inv);
    v1.z = f2bf(o1[4 * g + 2] * inv); v1.w = f2bf(o1[4 * g + 3] * inv);
    *(ushort4*)(op + d0) = v0;
    *(ushort4*)(op + 32 + d0) = v1;
  }
}

extern "C" void kernel_launch(void* const* d_in, const int* in_sizes, int n_in,
                              void* d_out, int out_size, void* d_ws, size_t ws_size,
                              hipStream_t stream) {
  const float* x   = (const float*)d_in[0];
  const float* WQw = (const float*)d_in[1];
  const float* WQb = (const float*)d_in[2];
  const float* WKw = (const float*)d_in[3];
  const float* WKb = (const float*)d_in[4];
  const float* WVw = (const float*)d_in[5];
  const float* WVb = (const float*)d_in[6];
  const float* WOw = (const float*)d_in[7];
  const float* WOb = (const float*)d_in[8];
  float* out = (float*)d_out;

  const int M = BATCH * SEQ;       // 8192
  const int D = D_MODEL;           // 1024
  const int NX = M * D;            // 8388608
  const int NW = D * D;            // 1048576

  unsigned short* xb = (unsigned short*)d_ws;
  unsigned short* wq = xb + NX;        // wq|wk|wv|wo contiguous (cvt4)
  unsigned short* wo = wq + 3 * NW;
  unsigned short* QKVb = wq + 4 * NW;  // [8192][3072]
  unsigned short* AOb = xb;            // reuse x-bf16 region after QKV projection

  cvt_kernel<<<NX / 8 / 256, 256, 0, stream>>>(x, xb, NX);
  cvt4_kernel<<<dim3(NW / 8 / 256, 4), 256, 0, stream>>>(WQw, WKw, WVw, WOw, wq, NW);

  const float qscale = 0.125f * 1.4426950408889634f;  // softmax scale + log2(e) folded into Q
  // fused QKV projection: [8192,1024] x [3072,1024]^T -> [8192,3072]
  gemm_bt<unsigned short><<<dim3(3 * D / 128, M / 128), 256, 0, stream>>>(
      xb, wq, WQb, WKb, WVb, QKVb, M, 3 * D, D, 1024, qscale);

  attn_kernel<<<1024, 256, 0, stream>>>(QKVb, AOb);

  gemm_bt<float><<<dim3(D / 128, M / 128), 256, 0, stream>>>(
      AOb, wo, WOb, WOb, WOb, out, M, D, D, 0, 1.0f);
}